// Round 1
// baseline (2043.655 us; speedup 1.0000x reference)
//
#include <hip/hip_runtime.h>

// MultiHeadAttention round 0: correctness-first bf16-MFMA pipeline.
// B=4 S=2048 F=1024 H=16 D=64.  Out: [out 8.4M f32][attn 268M f32].
// ws layout (u16/bf16): qh, kh, vh, vht, ctx  (5 x 16 MiB = 80 MiB)

typedef unsigned short u16;
typedef short bf16x8 __attribute__((ext_vector_type(8)));
typedef float f32x4 __attribute__((ext_vector_type(4)));

#define DEV __device__ __forceinline__

DEV u16 f2bf(float x) {
  union { float f; unsigned u; } c; c.f = x;
  unsigned r = (c.u + 0x7fffu + ((c.u >> 16) & 1u)) >> 16;  // RNE
  return (u16)r;
}

// Stage a [R rows x 32 cols] tile (row-major, leading dim ld) into LDS with
// row stride 48 (96B, keeps 16B alignment for ds_read_b128; breaks worst
// power-of-2 conflicts). fp32 sources are converted to bf16 inline.
template<typename T, int R>
DEV void load_tile(const T* __restrict__ src, int ld, u16* dst) {
  const int t = threadIdx.x;
  if constexpr (sizeof(T) == 4) {           // fp32 -> bf16
    constexpr int PER = R * 8 / 256;        // float4 vectors per thread
    #pragma unroll
    for (int i = 0; i < PER; i++) {
      int v = t + i * 256;
      int r = v >> 3, c = (v & 7) * 4;
      float4 f = *(const float4*)(src + (long)r * ld + c);
      ushort4 h;
      h.x = f2bf(f.x); h.y = f2bf(f.y); h.z = f2bf(f.z); h.w = f2bf(f.w);
      *(ushort4*)(dst + r * 48 + c) = h;
    }
  } else {                                  // bf16 passthrough, 16B vectors
    constexpr int PER = R * 4 / 256;
    #pragma unroll
    for (int i = 0; i < PER; i++) {
      int v = t + i * 256;
      int r = v >> 2, c = (v & 3) * 8;
      *(uint4*)(dst + r * 48 + c) = *(const uint4*)(src + (long)r * ld + c);
    }
  }
}

// NT GEMM: C[m][n] = sum_k A[m][k]*B[n][k], A:[M,K] B:[N,K] both K-contig.
// MFMA 16x16x32 bf16; block 256 thr = 2x2 waves; wave tile (BM/2)x(BN/2).
// A-frag: A[m=lane&15][k=(lane>>4)*8+j]; B-frag: B[n=lane&15][k=(lane>>4)*8+j]
// C/D:    col=lane&15, row=(lane>>4)*4+reg   (m89/m91-verified mappings)
// EPI: 0=proj(+bias, ->head layout bf16)  1=scores(*0.125 ->attn f32)
//      2=pv(->ctx concat bf16)            3=fc(+bias, relu ->out f32)
template<int BM, int BN, typename TA, typename TB, int EPI>
__global__ __launch_bounds__(256) void gemm_nt(
    const TA* __restrict__ A, const TB* __restrict__ B,
    const float* __restrict__ bias,
    float* __restrict__ outf, u16* __restrict__ outh,
    int lda, int ldb, int K, long azs, long bzs)
{
  constexpr int WTM = BM / 32, WTN = BN / 32;
  __shared__ u16 lA[BM * 48];
  __shared__ u16 lB[BN * 48];
  A += (long)blockIdx.z * azs + (long)blockIdx.x * BM * lda;
  B += (long)blockIdx.z * bzs + (long)blockIdx.y * BN * ldb;
  const int lane = threadIdx.x & 63, w = threadIdx.x >> 6;
  const int wm = (w & 1) * (BM / 2), wn = (w >> 1) * (BN / 2);
  const int l15 = lane & 15, q4 = lane >> 4;

  f32x4 acc[WTM][WTN] = {};

  for (int kt = 0; kt < K; kt += 32) {
    load_tile<TA, BM>(A + kt, lda, lA);
    load_tile<TB, BN>(B + kt, ldb, lB);
    __syncthreads();
    bf16x8 af[WTM], bv[WTN];
    #pragma unroll
    for (int i = 0; i < WTM; i++)
      af[i] = *(const bf16x8*)&lA[(wm + i * 16 + l15) * 48 + q4 * 8];
    #pragma unroll
    for (int j = 0; j < WTN; j++)
      bv[j] = *(const bf16x8*)&lB[(wn + j * 16 + l15) * 48 + q4 * 8];
    #pragma unroll
    for (int i = 0; i < WTM; i++)
      #pragma unroll
      for (int j = 0; j < WTN; j++)
        acc[i][j] = __builtin_amdgcn_mfma_f32_16x16x32_bf16(af[i], bv[j], acc[i][j], 0, 0, 0);
    __syncthreads();
  }

  const int bm0 = blockIdx.x * BM, bn0 = blockIdx.y * BN;
  #pragma unroll
  for (int i = 0; i < WTM; i++) {
    #pragma unroll
    for (int j = 0; j < WTN; j++) {
      const int col = bn0 + wn + j * 16 + l15;
      const int rb  = bm0 + wm + i * 16 + q4 * 4;
      float bvv = 0.f;
      if constexpr (EPI == 0 || EPI == 3) bvv = bias[col];
      #pragma unroll
      for (int r = 0; r < 4; r++) {
        const int row = rb + r;
        float val = acc[i][j][r];
        if constexpr (EPI == 0) {
          // token=row -> (b,s); feature=col -> (h,d); dst [B,H,S,D] bf16
          int b = row >> 11, s = row & 2047, hh = col >> 6, d = col & 63;
          outh[(((long)(b * 16 + hh) * 2048 + s)) * 64 + d] = f2bf(val + bvv);
        } else if constexpr (EPI == 1) {
          outf[(long)blockIdx.z * 4194304 + (long)row * 2048 + col] = val * 0.125f;
        } else if constexpr (EPI == 2) {
          int z = blockIdx.z, b = z >> 4, hh = z & 15;
          outh[((long)(b * 2048 + row)) * 1024 + hh * 64 + col] = f2bf(val);
        } else {
          outf[(long)row * 1024 + col] = fmaxf(val + bvv, 0.f);
        }
      }
    }
  }
}

// vh [z][s][d] -> vht [z][d][s], 64x64 tiles via LDS. z=b*H+h.
__global__ __launch_bounds__(256) void transpose_vh(
    const u16* __restrict__ vh, u16* __restrict__ vht)
{
  __shared__ u16 t[64 * 72];
  const int z = blockIdx.y, s0 = blockIdx.x * 64;
  const u16* src = vh + ((long)z * 2048 + s0) * 64;
  const int tid = threadIdx.x;
  #pragma unroll
  for (int i = 0; i < 2; i++) {
    int v = tid + i * 256;
    int r = v >> 3, c = (v & 7) * 8;
    *(uint4*)&t[r * 72 + c] = *(const uint4*)(src + r * 64 + c);
  }
  __syncthreads();
  u16* dst = vht + (long)z * 64 * 2048 + s0;
  #pragma unroll
  for (int i = 0; i < 2; i++) {
    int v = tid + i * 256;
    int d = v >> 3, c = (v & 7) * 8;   // c = s-offset in tile
    u16 tmp[8];
    #pragma unroll
    for (int j = 0; j < 8; j++) tmp[j] = t[(c + j) * 72 + d];
    *(uint4*)(dst + (long)d * 2048 + c) = *(uint4*)tmp;
  }
}

// in-place softmax over rows of 2048 fp32. one block per row.
__global__ __launch_bounds__(256) void softmax_rows(float* __restrict__ attn)
{
  float* p = attn + (long)blockIdx.x * 2048;
  const int t = threadIdx.x, w = t >> 6;
  float4* pv = (float4*)p;
  float4 a = pv[t], b = pv[t + 256];

  float m = fmaxf(fmaxf(fmaxf(a.x, a.y), fmaxf(a.z, a.w)),
                  fmaxf(fmaxf(b.x, b.y), fmaxf(b.z, b.w)));
  #pragma unroll
  for (int o = 32; o; o >>= 1) m = fmaxf(m, __shfl_xor(m, o));
  __shared__ float redm[4], reds[4];
  if ((t & 63) == 0) redm[w] = m;
  __syncthreads();
  m = fmaxf(fmaxf(redm[0], redm[1]), fmaxf(redm[2], redm[3]));

  a.x = __expf(a.x - m); a.y = __expf(a.y - m);
  a.z = __expf(a.z - m); a.w = __expf(a.w - m);
  b.x = __expf(b.x - m); b.y = __expf(b.y - m);
  b.z = __expf(b.z - m); b.w = __expf(b.w - m);
  float s = a.x + a.y + a.z + a.w + b.x + b.y + b.z + b.w;
  #pragma unroll
  for (int o = 32; o; o >>= 1) s += __shfl_xor(s, o);
  if ((t & 63) == 0) reds[w] = s;
  __syncthreads();
  s = reds[0] + reds[1] + reds[2] + reds[3];

  const float inv = 1.0f / s;
  a.x *= inv; a.y *= inv; a.z *= inv; a.w *= inv;
  b.x *= inv; b.y *= inv; b.z *= inv; b.w *= inv;
  pv[t] = a; pv[t + 256] = b;
}

extern "C" void kernel_launch(void* const* d_in, const int* in_sizes, int n_in,
                              void* d_out, int out_size, void* d_ws, size_t ws_size,
                              hipStream_t stream)
{
  const float* q    = (const float*)d_in[0];
  const float* k    = (const float*)d_in[1];
  const float* v    = (const float*)d_in[2];
  const float* wq_w = (const float*)d_in[3];
  const float* wq_b = (const float*)d_in[4];
  const float* wk_w = (const float*)d_in[5];
  const float* wk_b = (const float*)d_in[6];
  const float* wv_w = (const float*)d_in[7];
  const float* wv_b = (const float*)d_in[8];
  const float* fc_w = (const float*)d_in[9];
  const float* fc_b = (const float*)d_in[10];

  float* out  = (float*)d_out;
  float* attn = out + (long)4 * 2048 * 1024;   // 8,388,608 floats

  u16* qh  = (u16*)d_ws;          // [B,H,S,D] bf16
  u16* kh  = qh  + 8388608;
  u16* vh  = kh  + 8388608;
  u16* vht = vh  + 8388608;       // [B,H,D,S]
  u16* ctx = vht + 8388608;       // [B*S, F] bf16

  dim3 blk(256, 1, 1);

  // QKV projections: X[8192,1024] @ W[1024,1024]^T + b  -> head layout bf16
  gemm_nt<128, 128, float, float, 0><<<dim3(64, 8, 1), blk, 0, stream>>>(
      q, wq_w, wq_b, nullptr, qh, 1024, 1024, 1024, 0, 0);
  gemm_nt<128, 128, float, float, 0><<<dim3(64, 8, 1), blk, 0, stream>>>(
      k, wk_w, wk_b, nullptr, kh, 1024, 1024, 1024, 0, 0);
  gemm_nt<128, 128, float, float, 0><<<dim3(64, 8, 1), blk, 0, stream>>>(
      v, wv_w, wv_b, nullptr, vh, 1024, 1024, 1024, 0, 0);

  transpose_vh<<<dim3(32, 64, 1), blk, 0, stream>>>(vh, vht);

  // scores[z] = qh[z] @ kh[z]^T * 0.125 -> attn region (fp32, raw scores)
  gemm_nt<128, 128, u16, u16, 1><<<dim3(16, 16, 64), blk, 0, stream>>>(
      qh, kh, nullptr, attn, nullptr, 64, 64, 64,
      (long)2048 * 64, (long)2048 * 64);

  softmax_rows<<<dim3(131072, 1, 1), blk, 0, stream>>>(attn);

  // ctx[z] = attn[z] @ vht[z]^T   (A fp32, B bf16, N=64)
  gemm_nt<128, 64, float, u16, 2><<<dim3(16, 1, 64), blk, 0, stream>>>(
      attn, vht, nullptr, nullptr, ctx, 2048, 2048, 2048,
      (long)2048 * 2048, (long)64 * 2048);

  // out = relu(ctx @ fc_w^T + fc_b)
  gemm_nt<128, 128, u16, float, 3><<<dim3(64, 8, 1), blk, 0, stream>>>(
      ctx, fc_w, fc_b, out, nullptr, 1024, 1024, 1024, 0, 0);
}